// Round 4
// baseline (194.493 us; speedup 1.0000x reference)
//
#include <hip/hip_runtime.h>
#include <cmath>

// MXIntGELU via 4096-entry LUT (ex1 in [-8,7] x mantissa in [-128,127]).
// R3: same as R2 but nt-store through a native ext_vector_type (the builtin
// rejects HIP_vector_type structs). 16 floats/thread, 2-deep pipeline,
// non-temporal output stores.

typedef float floatx4 __attribute__((ext_vector_type(4)));

__device__ __forceinline__ float pow2i(int k) {
    union { unsigned u; float f; } c;
    c.u = (unsigned)(127 + k) << 23;
    return c.f;
}

__device__ __forceinline__ int block_exp(float amax) {
    // clip(floor(log2(max(amax, 2^-8))), -8, 7) -- exact via ilogb
    int e = ilogbf(fmaxf(amax, 0x1p-8f));
    return max(-8, min(7, e));
}

__global__ __launch_bounds__(256) void build_lut_kernel(float* __restrict__ lut) {
    const int idx = blockIdx.x * 256 + threadIdx.x;   // 0..4095
    const int e = (idx >> 8) - 8;
    const int m = (idx & 255) - 128;
    const float q = (float)m * pow2i(e - 7);
    float r = fmaxf(q, 0.f);                          // relu path
    if (q > -3.f && q < 3.f) {
        const float t = q / 1.41421356237309504880f;
        const float er = (float)erf((double)t);       // correctly-rounded f32 erf
        const float g = q * (er + 1.f) * 0.5f;
        float qg = rintf(g * 32.f);                   // 8b / 5 frac-bit hash quant
        qg = fminf(fmaxf(qg, -128.f), 127.f);
        const float qgelu = qg * 0.03125f;
        const float mg = floorf(qgelu * pow2i(7 - e)); // exponent-aligned floor
        r = mg * pow2i(e - 7);
    }
    lut[idx] = r;
}

__global__ __launch_bounds__(256) void mxint_gelu_lut_kernel(
    const float* __restrict__ in, float* __restrict__ out,
    const float* __restrict__ glut, unsigned n16)
{
    __shared__ float lut[4096];
    {   // fill LDS LUT: 256 threads x 4 x float4 (coalesced, conflict-free)
        const floatx4* g4 = reinterpret_cast<const floatx4*>(glut);
        floatx4* l4 = reinterpret_cast<floatx4*>(lut);
        #pragma unroll
        for (int k = 0; k < 4; ++k)
            l4[threadIdx.x + 256 * k] = g4[threadIdx.x + 256 * k];
    }
    __syncthreads();

    const unsigned stride = gridDim.x * 256u;
    unsigned u = blockIdx.x * 256u + threadIdx.x;

    floatx4 cur[4];
    bool have = (u < n16);
    if (have) {
        const floatx4* p = reinterpret_cast<const floatx4*>(in) + 4 * (size_t)u;
        cur[0] = p[0]; cur[1] = p[1]; cur[2] = p[2]; cur[3] = p[3];
    }

    while (have) {
        const unsigned un = u + stride;
        floatx4 nxt[4];
        const bool have_n = (un < n16);
        if (have_n) {   // prefetch next chunk before touching cur
            const floatx4* p = reinterpret_cast<const floatx4*>(in) + 4 * (size_t)un;
            nxt[0] = p[0]; nxt[1] = p[1]; nxt[2] = p[2]; nxt[3] = p[3];
        }

        float x[16];
        #pragma unroll
        for (int k = 0; k < 4; ++k) {
            x[4*k+0] = cur[k].x; x[4*k+1] = cur[k].y;
            x[4*k+2] = cur[k].z; x[4*k+3] = cur[k].w;
        }

        // thread owns 16 consecutive floats; a lane PAIR owns one 32-block
        float amax = 0.f;
        #pragma unroll
        for (int j = 0; j < 16; ++j) amax = fmaxf(amax, fabsf(x[j]));
        amax = fmaxf(amax, __shfl_xor(amax, 1, 64));

        const int ex1 = block_exp(amax);
        const float s1 = pow2i(7 - ex1);          // 128 / 2^ex1
        const int base = (ex1 + 8) * 256 + 128;

        float o[16];
        float oamax = 0.f;
        #pragma unroll
        for (int j = 0; j < 16; ++j) {
            float m = rintf(x[j] * s1);           // round-half-even
            m = fminf(fmaxf(m, -128.f), 127.f);
            const float r = lut[base + (int)m];
            o[j] = r;
            oamax = fmaxf(oamax, fabsf(r));
        }

        oamax = fmaxf(oamax, __shfl_xor(oamax, 1, 64));
        const int ex2 = block_exp(oamax);
        const float s2 = pow2i(7 - ex2);
        const float is2 = pow2i(ex2 - 7);

        floatx4* q = reinterpret_cast<floatx4*>(out) + 4 * (size_t)u;
        #pragma unroll
        for (int k = 0; k < 4; ++k) {
            floatx4 yv;
            float m0 = fminf(fmaxf(rintf(o[4*k+0] * s2), -128.f), 127.f);
            float m1 = fminf(fmaxf(rintf(o[4*k+1] * s2), -128.f), 127.f);
            float m2 = fminf(fmaxf(rintf(o[4*k+2] * s2), -128.f), 127.f);
            float m3 = fminf(fmaxf(rintf(o[4*k+3] * s2), -128.f), 127.f);
            yv.x = m0 * is2; yv.y = m1 * is2; yv.z = m2 * is2; yv.w = m3 * is2;
            __builtin_nontemporal_store(yv, q + k);
        }

        #pragma unroll
        for (int k = 0; k < 4; ++k) cur[k] = nxt[k];
        u = un;
        have = have_n;
    }
}

// Fallback (ws too small or n % 32 != 0): direct computation, identical numerics.
__global__ __launch_bounds__(256) void mxint_gelu_direct_kernel(
    const float* __restrict__ in, float* __restrict__ out, unsigned n4)
{
    unsigned i = blockIdx.x * 256u + threadIdx.x;
    if (i >= n4) return;
    const float4 xv = reinterpret_cast<const float4*>(in)[i];
    float x[4] = {xv.x, xv.y, xv.z, xv.w};
    float amax = fmaxf(fmaxf(fabsf(x[0]), fabsf(x[1])),
                       fmaxf(fabsf(x[2]), fabsf(x[3])));
    amax = fmaxf(amax, __shfl_xor(amax, 1, 64));
    amax = fmaxf(amax, __shfl_xor(amax, 2, 64));
    amax = fmaxf(amax, __shfl_xor(amax, 4, 64));
    const int ex1 = block_exp(amax);
    const float s1 = pow2i(7 - ex1), is1 = pow2i(ex1 - 7);
    float o[4]; float oamax = 0.f;
    #pragma unroll
    for (int j = 0; j < 4; ++j) {
        float m = rintf(x[j] * s1);
        m = fminf(fmaxf(m, -128.f), 127.f);
        const float q = m * is1;
        float r = fmaxf(q, 0.f);
        if (q > -3.f && q < 3.f) {
            const float t = q / 1.41421356237309504880f;
            const float e = (float)erf((double)t);
            const float g = q * (e + 1.f) * 0.5f;
            float qg = rintf(g * 32.f);
            qg = fminf(fmaxf(qg, -128.f), 127.f);
            const float mg = floorf(qg * 0.03125f * s1);
            r = mg * is1;
        }
        o[j] = r; oamax = fmaxf(oamax, fabsf(r));
    }
    oamax = fmaxf(oamax, __shfl_xor(oamax, 1, 64));
    oamax = fmaxf(oamax, __shfl_xor(oamax, 2, 64));
    oamax = fmaxf(oamax, __shfl_xor(oamax, 4, 64));
    const int ex2 = block_exp(oamax);
    const float s2 = pow2i(7 - ex2), is2 = pow2i(ex2 - 7);
    float y[4];
    #pragma unroll
    for (int j = 0; j < 4; ++j) {
        float m = rintf(o[j] * s2);
        m = fminf(fmaxf(m, -128.f), 127.f);
        y[j] = m * is2;
    }
    reinterpret_cast<float4*>(out)[i] =
        make_float4(y[0], y[1], y[2], y[3]);
}

extern "C" void kernel_launch(void* const* d_in, const int* in_sizes, int n_in,
                              void* d_out, int out_size, void* d_ws, size_t ws_size,
                              hipStream_t stream) {
    const float* x = (const float*)d_in[0];
    float* y = (float*)d_out;
    const unsigned n = (unsigned)in_sizes[0];   // 33,554,432

    if (ws_size >= 4096 * sizeof(float) && (n % 32u) == 0u) {
        float* lut = (float*)d_ws;
        build_lut_kernel<<<16, 256, 0, stream>>>(lut);
        const unsigned n16 = n / 16;
        unsigned blocks = 2048;                 // 8 blocks/CU, grid-stride
        if (blocks * 256u > n16) blocks = (n16 + 255u) / 256u;
        mxint_gelu_lut_kernel<<<blocks, 256, 0, stream>>>(x, y, lut, n16);
    } else {
        const unsigned n4 = n / 4;
        mxint_gelu_direct_kernel<<<(n4 + 255u) / 256u, 256, 0, stream>>>(x, y, n4);
    }
}

// Round 5
// 57.522 us; speedup vs baseline: 3.3812x; 3.3812x over previous
//
#include <hip/hip_runtime.h>
#include <cmath>

// MXIntGELU via 4096-entry LUT (ex1 in [-8,7] x mantissa in [-128,127]).
// R4: revert nt-stores (they caused 2.6x write amplification -- nt bypasses
// L2 write-combining on gfx950). Keep 16 floats/thread + 2-deep prefetch.

typedef float floatx4 __attribute__((ext_vector_type(4)));

__device__ __forceinline__ float pow2i(int k) {
    union { unsigned u; float f; } c;
    c.u = (unsigned)(127 + k) << 23;
    return c.f;
}

__device__ __forceinline__ int block_exp(float amax) {
    // clip(floor(log2(max(amax, 2^-8))), -8, 7) -- exact via ilogb
    int e = ilogbf(fmaxf(amax, 0x1p-8f));
    return max(-8, min(7, e));
}

__global__ __launch_bounds__(256) void build_lut_kernel(float* __restrict__ lut) {
    const int idx = blockIdx.x * 256 + threadIdx.x;   // 0..4095
    const int e = (idx >> 8) - 8;
    const int m = (idx & 255) - 128;
    const float q = (float)m * pow2i(e - 7);
    float r = fmaxf(q, 0.f);                          // relu path
    if (q > -3.f && q < 3.f) {
        const float t = q / 1.41421356237309504880f;
        const float er = (float)erf((double)t);       // correctly-rounded f32 erf
        const float g = q * (er + 1.f) * 0.5f;
        float qg = rintf(g * 32.f);                   // 8b / 5 frac-bit hash quant
        qg = fminf(fmaxf(qg, -128.f), 127.f);
        const float qgelu = qg * 0.03125f;
        const float mg = floorf(qgelu * pow2i(7 - e)); // exponent-aligned floor
        r = mg * pow2i(e - 7);
    }
    lut[idx] = r;
}

__global__ __launch_bounds__(256) void mxint_gelu_lut_kernel(
    const float* __restrict__ in, float* __restrict__ out,
    const float* __restrict__ glut, unsigned n16)
{
    __shared__ float lut[4096];
    {   // fill LDS LUT: 256 threads x 4 x float4 (coalesced, conflict-free)
        const floatx4* g4 = reinterpret_cast<const floatx4*>(glut);
        floatx4* l4 = reinterpret_cast<floatx4*>(lut);
        #pragma unroll
        for (int k = 0; k < 4; ++k)
            l4[threadIdx.x + 256 * k] = g4[threadIdx.x + 256 * k];
    }
    __syncthreads();

    const unsigned stride = gridDim.x * 256u;
    unsigned u = blockIdx.x * 256u + threadIdx.x;

    floatx4 cur[4];
    bool have = (u < n16);
    if (have) {
        const floatx4* p = reinterpret_cast<const floatx4*>(in) + 4 * (size_t)u;
        cur[0] = p[0]; cur[1] = p[1]; cur[2] = p[2]; cur[3] = p[3];
    }

    while (have) {
        const unsigned un = u + stride;
        floatx4 nxt[4];
        const bool have_n = (un < n16);
        if (have_n) {   // prefetch next chunk before touching cur
            const floatx4* p = reinterpret_cast<const floatx4*>(in) + 4 * (size_t)un;
            nxt[0] = p[0]; nxt[1] = p[1]; nxt[2] = p[2]; nxt[3] = p[3];
        }

        float x[16];
        #pragma unroll
        for (int k = 0; k < 4; ++k) {
            x[4*k+0] = cur[k].x; x[4*k+1] = cur[k].y;
            x[4*k+2] = cur[k].z; x[4*k+3] = cur[k].w;
        }

        // thread owns 16 consecutive floats; a lane PAIR owns one 32-block
        float amax = 0.f;
        #pragma unroll
        for (int j = 0; j < 16; ++j) amax = fmaxf(amax, fabsf(x[j]));
        amax = fmaxf(amax, __shfl_xor(amax, 1, 64));

        const int ex1 = block_exp(amax);
        const float s1 = pow2i(7 - ex1);          // 128 / 2^ex1
        const int base = (ex1 + 8) * 256 + 128;

        float o[16];
        float oamax = 0.f;
        #pragma unroll
        for (int j = 0; j < 16; ++j) {
            float m = rintf(x[j] * s1);           // round-half-even
            m = fminf(fmaxf(m, -128.f), 127.f);
            const float r = lut[base + (int)m];
            o[j] = r;
            oamax = fmaxf(oamax, fabsf(r));
        }

        oamax = fmaxf(oamax, __shfl_xor(oamax, 1, 64));
        const int ex2 = block_exp(oamax);
        const float s2 = pow2i(7 - ex2);
        const float is2 = pow2i(ex2 - 7);

        floatx4* q = reinterpret_cast<floatx4*>(out) + 4 * (size_t)u;
        #pragma unroll
        for (int k = 0; k < 4; ++k) {
            floatx4 yv;
            float m0 = fminf(fmaxf(rintf(o[4*k+0] * s2), -128.f), 127.f);
            float m1 = fminf(fmaxf(rintf(o[4*k+1] * s2), -128.f), 127.f);
            float m2 = fminf(fmaxf(rintf(o[4*k+2] * s2), -128.f), 127.f);
            float m3 = fminf(fmaxf(rintf(o[4*k+3] * s2), -128.f), 127.f);
            yv.x = m0 * is2; yv.y = m1 * is2; yv.z = m2 * is2; yv.w = m3 * is2;
            q[k] = yv;
        }

        #pragma unroll
        for (int k = 0; k < 4; ++k) cur[k] = nxt[k];
        u = un;
        have = have_n;
    }
}

// Fallback (ws too small or n % 32 != 0): direct computation, identical numerics.
__global__ __launch_bounds__(256) void mxint_gelu_direct_kernel(
    const float* __restrict__ in, float* __restrict__ out, unsigned n4)
{
    unsigned i = blockIdx.x * 256u + threadIdx.x;
    if (i >= n4) return;
    const float4 xv = reinterpret_cast<const float4*>(in)[i];
    float x[4] = {xv.x, xv.y, xv.z, xv.w};
    float amax = fmaxf(fmaxf(fabsf(x[0]), fabsf(x[1])),
                       fmaxf(fabsf(x[2]), fabsf(x[3])));
    amax = fmaxf(amax, __shfl_xor(amax, 1, 64));
    amax = fmaxf(amax, __shfl_xor(amax, 2, 64));
    amax = fmaxf(amax, __shfl_xor(amax, 4, 64));
    const int ex1 = block_exp(amax);
    const float s1 = pow2i(7 - ex1), is1 = pow2i(ex1 - 7);
    float o[4]; float oamax = 0.f;
    #pragma unroll
    for (int j = 0; j < 4; ++j) {
        float m = rintf(x[j] * s1);
        m = fminf(fmaxf(m, -128.f), 127.f);
        const float q = m * is1;
        float r = fmaxf(q, 0.f);
        if (q > -3.f && q < 3.f) {
            const float t = q / 1.41421356237309504880f;
            const float e = (float)erf((double)t);
            const float g = q * (e + 1.f) * 0.5f;
            float qg = rintf(g * 32.f);
            qg = fminf(fmaxf(qg, -128.f), 127.f);
            const float mg = floorf(qg * 0.03125f * s1);
            r = mg * is1;
        }
        o[j] = r; oamax = fmaxf(oamax, fabsf(r));
    }
    oamax = fmaxf(oamax, __shfl_xor(oamax, 1, 64));
    oamax = fmaxf(oamax, __shfl_xor(oamax, 2, 64));
    oamax = fmaxf(oamax, __shfl_xor(oamax, 4, 64));
    const int ex2 = block_exp(oamax);
    const float s2 = pow2i(7 - ex2), is2 = pow2i(ex2 - 7);
    float y[4];
    #pragma unroll
    for (int j = 0; j < 4; ++j) {
        float m = rintf(o[j] * s2);
        m = fminf(fmaxf(m, -128.f), 127.f);
        y[j] = m * is2;
    }
    reinterpret_cast<float4*>(out)[i] =
        make_float4(y[0], y[1], y[2], y[3]);
}

extern "C" void kernel_launch(void* const* d_in, const int* in_sizes, int n_in,
                              void* d_out, int out_size, void* d_ws, size_t ws_size,
                              hipStream_t stream) {
    const float* x = (const float*)d_in[0];
    float* y = (float*)d_out;
    const unsigned n = (unsigned)in_sizes[0];   // 33,554,432

    if (ws_size >= 4096 * sizeof(float) && (n % 32u) == 0u) {
        float* lut = (float*)d_ws;
        build_lut_kernel<<<16, 256, 0, stream>>>(lut);
        const unsigned n16 = n / 16;
        unsigned blocks = 2048;                 // 8 blocks/CU, grid-stride
        if (blocks * 256u > n16) blocks = (n16 + 255u) / 256u;
        mxint_gelu_lut_kernel<<<blocks, 256, 0, stream>>>(x, y, lut, n16);
    } else {
        const unsigned n4 = n / 4;
        mxint_gelu_direct_kernel<<<(n4 + 255u) / 256u, 256, 0, stream>>>(x, y, n4);
    }
}

// Round 6
// 53.743 us; speedup vs baseline: 3.6189x; 1.0703x over previous
//
#include <hip/hip_runtime.h>
#include <cmath>

// MXIntGELU via 4096-entry LUT (ex1 in [-8,7] x mantissa in [-128,127]).
// R5: back to 8 floats/thread (R2's best). 2-deep prefetch with SMALL payload
// (cur[2]/nxt[2] = 16 VGPR) so the compiler keeps it; 512-thread blocks to
// halve LUT-staging overhead. Numerics identical -> absmax 0.0.

typedef float floatx4 __attribute__((ext_vector_type(4)));

__device__ __forceinline__ float pow2i(int k) {
    union { unsigned u; float f; } c;
    c.u = (unsigned)(127 + k) << 23;
    return c.f;
}

__device__ __forceinline__ int block_exp(float amax) {
    // clip(floor(log2(max(amax, 2^-8))), -8, 7) -- exact via ilogb
    int e = ilogbf(fmaxf(amax, 0x1p-8f));
    return max(-8, min(7, e));
}

__global__ __launch_bounds__(256) void build_lut_kernel(float* __restrict__ lut) {
    const int idx = blockIdx.x * 256 + threadIdx.x;   // 0..4095
    const int e = (idx >> 8) - 8;
    const int m = (idx & 255) - 128;
    const float q = (float)m * pow2i(e - 7);
    float r = fmaxf(q, 0.f);                          // relu path
    if (q > -3.f && q < 3.f) {
        const float t = q / 1.41421356237309504880f;
        const float er = (float)erf((double)t);       // correctly-rounded f32 erf
        const float g = q * (er + 1.f) * 0.5f;
        float qg = rintf(g * 32.f);                   // 8b / 5 frac-bit hash quant
        qg = fminf(fmaxf(qg, -128.f), 127.f);
        const float qgelu = qg * 0.03125f;
        const float mg = floorf(qgelu * pow2i(7 - e)); // exponent-aligned floor
        r = mg * pow2i(e - 7);
    }
    lut[idx] = r;
}

__global__ __launch_bounds__(512) void mxint_gelu_lut_kernel(
    const float* __restrict__ in, float* __restrict__ out,
    const float* __restrict__ glut, unsigned n8)
{
    __shared__ float lut[4096];
    {   // fill LDS LUT: 512 threads x 2 x float4 (coalesced, conflict-free)
        const floatx4* g4 = reinterpret_cast<const floatx4*>(glut);
        floatx4* l4 = reinterpret_cast<floatx4*>(lut);
        #pragma unroll
        for (int k = 0; k < 2; ++k)
            l4[threadIdx.x + 512 * k] = g4[threadIdx.x + 512 * k];
    }
    __syncthreads();

    const unsigned stride = gridDim.x * 512u;
    unsigned u = blockIdx.x * 512u + threadIdx.x;

    floatx4 cur0, cur1;
    bool have = (u < n8);
    if (have) {
        const floatx4* p = reinterpret_cast<const floatx4*>(in) + 2 * (size_t)u;
        cur0 = p[0]; cur1 = p[1];
    }

    while (have) {
        const unsigned un = u + stride;
        floatx4 nxt0, nxt1;
        const bool have_n = (un < n8);
        if (have_n) {   // prefetch next chunk before touching cur
            const floatx4* p = reinterpret_cast<const floatx4*>(in) + 2 * (size_t)un;
            nxt0 = p[0]; nxt1 = p[1];
        }

        float x[8] = {cur0.x, cur0.y, cur0.z, cur0.w,
                      cur1.x, cur1.y, cur1.z, cur1.w};

        // thread owns 8 consecutive floats; a lane QUAD owns one 32-block
        float amax = 0.f;
        #pragma unroll
        for (int j = 0; j < 8; ++j) amax = fmaxf(amax, fabsf(x[j]));
        amax = fmaxf(amax, __shfl_xor(amax, 1, 64));
        amax = fmaxf(amax, __shfl_xor(amax, 2, 64));

        const int ex1 = block_exp(amax);
        const float s1 = pow2i(7 - ex1);          // 128 / 2^ex1
        const int base = (ex1 + 8) * 256 + 128;

        float o[8];
        float oamax = 0.f;
        #pragma unroll
        for (int j = 0; j < 8; ++j) {
            float m = rintf(x[j] * s1);           // round-half-even
            m = fminf(fmaxf(m, -128.f), 127.f);
            const float r = lut[base + (int)m];
            o[j] = r;
            oamax = fmaxf(oamax, fabsf(r));
        }

        oamax = fmaxf(oamax, __shfl_xor(oamax, 1, 64));
        oamax = fmaxf(oamax, __shfl_xor(oamax, 2, 64));
        const int ex2 = block_exp(oamax);
        const float s2 = pow2i(7 - ex2);
        const float is2 = pow2i(ex2 - 7);

        floatx4* q = reinterpret_cast<floatx4*>(out) + 2 * (size_t)u;
        #pragma unroll
        for (int k = 0; k < 2; ++k) {
            floatx4 yv;
            float m0 = fminf(fmaxf(rintf(o[4*k+0] * s2), -128.f), 127.f);
            float m1 = fminf(fmaxf(rintf(o[4*k+1] * s2), -128.f), 127.f);
            float m2 = fminf(fmaxf(rintf(o[4*k+2] * s2), -128.f), 127.f);
            float m3 = fminf(fmaxf(rintf(o[4*k+3] * s2), -128.f), 127.f);
            yv.x = m0 * is2; yv.y = m1 * is2; yv.z = m2 * is2; yv.w = m3 * is2;
            q[k] = yv;
        }

        cur0 = nxt0; cur1 = nxt1;
        u = un;
        have = have_n;
    }
}

// Fallback (ws too small or n % 32 != 0): direct computation, identical numerics.
__global__ __launch_bounds__(256) void mxint_gelu_direct_kernel(
    const float* __restrict__ in, float* __restrict__ out, unsigned n4)
{
    unsigned i = blockIdx.x * 256u + threadIdx.x;
    if (i >= n4) return;
    const float4 xv = reinterpret_cast<const float4*>(in)[i];
    float x[4] = {xv.x, xv.y, xv.z, xv.w};
    float amax = fmaxf(fmaxf(fabsf(x[0]), fabsf(x[1])),
                       fmaxf(fabsf(x[2]), fabsf(x[3])));
    amax = fmaxf(amax, __shfl_xor(amax, 1, 64));
    amax = fmaxf(amax, __shfl_xor(amax, 2, 64));
    amax = fmaxf(amax, __shfl_xor(amax, 4, 64));
    const int ex1 = block_exp(amax);
    const float s1 = pow2i(7 - ex1), is1 = pow2i(ex1 - 7);
    float o[4]; float oamax = 0.f;
    #pragma unroll
    for (int j = 0; j < 4; ++j) {
        float m = rintf(x[j] * s1);
        m = fminf(fmaxf(m, -128.f), 127.f);
        const float q = m * is1;
        float r = fmaxf(q, 0.f);
        if (q > -3.f && q < 3.f) {
            const float t = q / 1.41421356237309504880f;
            const float e = (float)erf((double)t);
            const float g = q * (e + 1.f) * 0.5f;
            float qg = rintf(g * 32.f);
            qg = fminf(fmaxf(qg, -128.f), 127.f);
            const float mg = floorf(qg * 0.03125f * s1);
            r = mg * is1;
        }
        o[j] = r; oamax = fmaxf(oamax, fabsf(r));
    }
    oamax = fmaxf(oamax, __shfl_xor(oamax, 1, 64));
    oamax = fmaxf(oamax, __shfl_xor(oamax, 2, 64));
    oamax = fmaxf(oamax, __shfl_xor(oamax, 4, 64));
    const int ex2 = block_exp(oamax);
    const float s2 = pow2i(7 - ex2), is2 = pow2i(ex2 - 7);
    float y[4];
    #pragma unroll
    for (int j = 0; j < 4; ++j) {
        float m = rintf(o[j] * s2);
        m = fminf(fmaxf(m, -128.f), 127.f);
        y[j] = m * is2;
    }
    reinterpret_cast<float4*>(out)[i] =
        make_float4(y[0], y[1], y[2], y[3]);
}

extern "C" void kernel_launch(void* const* d_in, const int* in_sizes, int n_in,
                              void* d_out, int out_size, void* d_ws, size_t ws_size,
                              hipStream_t stream) {
    const float* x = (const float*)d_in[0];
    float* y = (float*)d_out;
    const unsigned n = (unsigned)in_sizes[0];   // 33,554,432

    if (ws_size >= 4096 * sizeof(float) && (n % 32u) == 0u) {
        float* lut = (float*)d_ws;
        build_lut_kernel<<<16, 256, 0, stream>>>(lut);
        const unsigned n8 = n / 8;
        unsigned blocks = 1024;                 // 4 blocks/CU x 512 thr = full occ
        if (blocks * 512u > n8) blocks = (n8 + 511u) / 512u;
        mxint_gelu_lut_kernel<<<blocks, 512, 0, stream>>>(x, y, lut, n8);
    } else {
        const unsigned n4 = n / 4;
        mxint_gelu_direct_kernel<<<(n4 + 255u) / 256u, 256, 0, stream>>>(x, y, n4);
    }
}